// Round 15
// baseline (595.894 us; speedup 1.0000x reference)
//
#include <hip/hip_runtime.h>
#include <hip/hip_fp8.h>
#include <math.h>

#define NN 100000
#define NE 3200000
#define FIN 128
#define HD 256
#define CO 47
#define NBKT 196   // buckets of 512 nodes: dst>>9
#define G 1024     // partition blocks
#define CHUNK 3125 // NE / G exactly

typedef _Float16 h2 __attribute__((ext_vector_type(2)));
typedef _Float16 h4 __attribute__((ext_vector_type(4)));
typedef _Float16 h8 __attribute__((ext_vector_type(8)));
typedef float f32x2 __attribute__((ext_vector_type(2)));
typedef float f32x4 __attribute__((ext_vector_type(4)));
typedef unsigned int u32x2 __attribute__((ext_vector_type(2)));
typedef unsigned int u32x4 __attribute__((ext_vector_type(4)));

// ---------------- CSR build via bucketed counting sort ----------------

__global__ __launch_bounds__(256) void hist_kernel(const int* __restrict__ dst,
                                                   int* __restrict__ hist) {
    __shared__ int h[NBKT];
    int tid = threadIdx.x;
    for (int i = tid; i < NBKT; i += 256) h[i] = 0;
    __syncthreads();
    int base = blockIdx.x * CHUNK;
    for (int i = tid; i < CHUNK; i += 256)
        atomicAdd(&h[dst[base + i] >> 9], 1);
    __syncthreads();
    for (int i = tid; i < NBKT; i += 256) hist[i * G + blockIdx.x] = h[i];
}

__global__ __launch_bounds__(256) void rowscan_kernel(int* __restrict__ hist,
                                                      int* __restrict__ btot) {
    __shared__ int sums[256];
    int b = blockIdx.x, t = threadIdx.x;
    int base = b * G + t * 4;
    int4 v = *(int4*)&hist[base];
    int i0 = v.x, i1 = i0 + v.y, i2 = i1 + v.z, i3 = i2 + v.w;
    sums[t] = i3;
    __syncthreads();
    #pragma unroll
    for (int off = 1; off < 256; off <<= 1) {
        int u = (t >= off) ? sums[t - off] : 0;
        __syncthreads();
        sums[t] += u;
        __syncthreads();
    }
    int excl = sums[t] - i3;
    hist[base] = excl;
    hist[base + 1] = excl + i0;
    hist[base + 2] = excl + i1;
    hist[base + 3] = excl + i2;
    if (t == 255) btot[b] = sums[255];
}

__global__ void totscan_kernel(const int* __restrict__ btot, int* __restrict__ bbase) {
    __shared__ int tmp[256];
    int t = threadIdx.x;
    int v = (t < NBKT) ? btot[t] : 0;
    tmp[t] = v;
    __syncthreads();
    #pragma unroll
    for (int off = 1; off < 256; off <<= 1) {
        int u = (t >= off) ? tmp[t - off] : 0;
        __syncthreads();
        tmp[t] += u;
        __syncthreads();
    }
    if (t < NBKT) bbase[t] = tmp[t] - v;
    if (t == NBKT - 1) bbase[NBKT] = tmp[t];
}

__global__ __launch_bounds__(256) void scatter_kernel(const int* __restrict__ src,
                                                      const int* __restrict__ dst,
                                                      const int* __restrict__ hscan,
                                                      const int* __restrict__ bbase,
                                                      int* __restrict__ epk) {
    __shared__ int cur[NBKT];
    int tid = threadIdx.x;
    for (int i = tid; i < NBKT; i += 256)
        cur[i] = hscan[i * G + blockIdx.x] + bbase[i];
    __syncthreads();
    int base = blockIdx.x * CHUNK;
    for (int i = tid; i < CHUNK; i += 256) {
        int e = base + i;
        int d = dst[e];
        int slot = atomicAdd(&cur[d >> 9], 1);
        epk[slot] = ((d & 511) << 17) | src[e];
    }
}

__global__ __launch_bounds__(256) void bucket_fill_kernel(
    const int* __restrict__ bbase, const int* __restrict__ epk,
    int* __restrict__ csr, int* __restrict__ offs, float* __restrict__ dinv)
{
    __shared__ int deg[512], cur[512], a0[512], a1[512];
    int tid = threadIdx.x, b = blockIdx.x;
    int ebeg = bbase[b], eend = bbase[b + 1];
    deg[tid] = 0; deg[tid + 256] = 0;
    __syncthreads();
    for (int e = ebeg + tid; e < eend; e += 256)
        atomicAdd(&deg[((unsigned)epk[e]) >> 17], 1);
    __syncthreads();
    a0[tid] = deg[tid]; a0[tid + 256] = deg[tid + 256];
    __syncthreads();
    int* pin = a0; int* pout = a1;
    for (int off = 1; off < 512; off <<= 1) {
        #pragma unroll
        for (int q = 0; q < 2; ++q) {
            int p = tid + q * 256;
            pout[p] = pin[p] + ((p >= off) ? pin[p - off] : 0);
        }
        __syncthreads();
        int* t = pin; pin = pout; pout = t;
    }
    #pragma unroll
    for (int q = 0; q < 2; ++q) {
        int i = tid + q * 256;
        int excl = pin[i] - deg[i];
        cur[i] = excl;
        int node = b * 512 + i;
        if (node < NN) {
            offs[node] = ebeg + excl;
            dinv[node] = rsqrtf((float)deg[i] + 1.0f);
        }
    }
    if (b == 0 && tid == 0) offs[NN] = NE;
    __syncthreads();
    for (int e = ebeg + tid; e < eend; e += 256) {
        int pk = epk[e];
        int p = atomicAdd(&cur[((unsigned)pk) >> 17], 1);
        csr[ebeg + p] = pk & 0x1FFFF;
    }
}

// ---------------- weight convert (all three, one launch) ----------------

__global__ void wtrans_all_kernel(const float* __restrict__ W0,
                                  const float* __restrict__ W1,
                                  const float* __restrict__ W2,
                                  _Float16* __restrict__ wt0,
                                  _Float16* __restrict__ wt1,
                                  _Float16* __restrict__ wt2) {
    int i = blockIdx.x * 256 + threadIdx.x;
    if (i < 256 * 128) {                       // wt0[n][k] = W0[k][n], [256][128]
        int n = i >> 7, k = i & 127;
        wt0[i] = (_Float16)W0[k * 256 + n];
    } else if (i < 256 * 128 + 256 * 256) {    // wt1[n][k] = W1[k][n], [256][256]
        int t = i - 256 * 128;
        int n = t >> 8, k = t & 255;
        wt1[t] = (_Float16)W1[k * 256 + n];
    } else if (i < 256 * 128 + 256 * 256 + 64 * 256) {  // wt2[n][k], n>=CO zero
        int t = i - 256 * 128 - 256 * 256;
        int n = t >> 8, k = t & 255;
        wt2[t] = (_Float16)((n < CO) ? W2[k * CO + n] : 0.0f);
    }
}

// ---------------- x -> fp8 e4m3 (OCP) via HW cvt, pre-scaled by dinv ----------------

__global__ void conv_x_kernel(const float* __restrict__ x, const float* __restrict__ dinv,
                              unsigned* __restrict__ xq) {
    int i = blockIdx.x * 256 + threadIdx.x;     // over NN*FIN/4
    if (i >= NN * FIN / 4) return;
    int r = i >> 5;
    float4 v = ((const float4*)x)[i];
    float dv = dinv[r];
    int u = __builtin_amdgcn_cvt_pk_fp8_f32(v.x * dv, v.y * dv, 0, false);
    u = __builtin_amdgcn_cvt_pk_fp8_f32(v.z * dv, v.w * dv, u, true);
    xq[i] = (unsigned)u;
}

// ---------------- aggregation (wave per node, atomic-free, HW fp8 decode) --------
// agg128: 4 lane-groups of 16; each group a different edge; lane loads u32x2 (8B).

__global__ __launch_bounds__(256) void agg128_kernel(
    const unsigned* __restrict__ xq, const int* __restrict__ offs,
    const int* __restrict__ csr, const float* __restrict__ dinv,
    _Float16* __restrict__ out)
{
    int lane = threadIdx.x & 63;
    int grp = lane >> 4;          // 0..3
    int gl = lane & 15;           // u32x2 slot within row (8 cols)
    int v = blockIdx.x * 4 + (threadIdx.x >> 6);
    const u32x2* rows = (const u32x2*)xq;   // 16 per row
    f32x2 c0 = {0.f, 0.f}, c1 = {0.f, 0.f}, c2 = {0.f, 0.f}, c3 = {0.f, 0.f};
    if (grp == 0) {
        u32x2 u = rows[(size_t)v * 16 + gl];          // self loop
        c0 += __builtin_amdgcn_cvt_pk_f32_fp8((int)u[0], false);
        c1 += __builtin_amdgcn_cvt_pk_f32_fp8((int)u[0], true);
        c2 += __builtin_amdgcn_cvt_pk_f32_fp8((int)u[1], false);
        c3 += __builtin_amdgcn_cvt_pk_f32_fp8((int)u[1], true);
    }
    int b = offs[v], e = offs[v + 1];
    int j = b + grp;              // group g takes edges b+g, b+g+4, ...
    int s[8];
    bool have = (j + 28 < e);
    if (have) {
        #pragma unroll
        for (int q = 0; q < 8; ++q) s[q] = csr[j + 4 * q];
    }
    while (have) {
        int nj = j + 32;
        bool nhave = (nj + 28 < e);
        int ns[8];
        if (nhave) {
            #pragma unroll
            for (int q = 0; q < 8; ++q) ns[q] = csr[nj + 4 * q];
        }
        #pragma unroll
        for (int q = 0; q < 8; ++q) {
            u32x2 t = rows[(size_t)s[q] * 16 + gl];
            c0 += __builtin_amdgcn_cvt_pk_f32_fp8((int)t[0], false);
            c1 += __builtin_amdgcn_cvt_pk_f32_fp8((int)t[0], true);
            c2 += __builtin_amdgcn_cvt_pk_f32_fp8((int)t[1], false);
            c3 += __builtin_amdgcn_cvt_pk_f32_fp8((int)t[1], true);
        }
        #pragma unroll
        for (int q = 0; q < 8; ++q) s[q] = ns[q];
        j = nj; have = nhave;
    }
    for (; j < e; j += 4) {
        u32x2 t = rows[(size_t)csr[j] * 16 + gl];
        c0 += __builtin_amdgcn_cvt_pk_f32_fp8((int)t[0], false);
        c1 += __builtin_amdgcn_cvt_pk_f32_fp8((int)t[0], true);
        c2 += __builtin_amdgcn_cvt_pk_f32_fp8((int)t[1], false);
        c3 += __builtin_amdgcn_cvt_pk_f32_fp8((int)t[1], true);
    }
    // cross-group reduce: lanes ^16 and ^32 hold other edge sublists
    #pragma unroll
    for (int o = 16; o <= 32; o <<= 1) {
        c0[0] += __shfl_xor(c0[0], o, 64); c0[1] += __shfl_xor(c0[1], o, 64);
        c1[0] += __shfl_xor(c1[0], o, 64); c1[1] += __shfl_xor(c1[1], o, 64);
        c2[0] += __shfl_xor(c2[0], o, 64); c2[1] += __shfl_xor(c2[1], o, 64);
        c3[0] += __shfl_xor(c3[0], o, 64); c3[1] += __shfl_xor(c3[1], o, 64);
    }
    if (grp == 0) {
        float dv = dinv[v];
        h8 o8;
        o8[0] = (_Float16)(c0[0] * dv); o8[1] = (_Float16)(c0[1] * dv);
        o8[2] = (_Float16)(c1[0] * dv); o8[3] = (_Float16)(c1[1] * dv);
        o8[4] = (_Float16)(c2[0] * dv); o8[5] = (_Float16)(c2[1] * dv);
        o8[6] = (_Float16)(c3[0] * dv); o8[7] = (_Float16)(c3[1] * dv);
        ((h8*)out)[(size_t)v * 16 + gl] = o8;
    }
}

// t1 fp8 gather -> h1 written as fp8 (packed u32); proven 8-deep full-wave config
__global__ __launch_bounds__(256) void agg256_kernel(
    const unsigned* __restrict__ t1q, const int* __restrict__ offs,
    const int* __restrict__ csr, const float* __restrict__ dinv,
    unsigned* __restrict__ out)
{
    int lane = threadIdx.x & 63;
    int v = blockIdx.x * 4 + (threadIdx.x >> 6);
    unsigned sv = t1q[(size_t)v * 64 + lane];   // 4 fp8 per lane
    f32x2 acc01 = __builtin_amdgcn_cvt_pk_f32_fp8((int)sv, false);
    f32x2 acc23 = __builtin_amdgcn_cvt_pk_f32_fp8((int)sv, true);
    int b = offs[v], e = offs[v + 1], j = b;
    int s[8];
    if (j + 8 <= e) {
        #pragma unroll
        for (int q = 0; q < 8; ++q) s[q] = csr[j + q];
    }
    for (; j + 8 <= e; ) {
        int nj = j + 8;
        int ns[8];
        if (nj + 8 <= e) {
            #pragma unroll
            for (int q = 0; q < 8; ++q) ns[q] = csr[nj + q];
        }
        #pragma unroll
        for (int q = 0; q < 8; ++q) {
            unsigned t = t1q[(size_t)s[q] * 64 + lane];
            acc01 += __builtin_amdgcn_cvt_pk_f32_fp8((int)t, false);
            acc23 += __builtin_amdgcn_cvt_pk_f32_fp8((int)t, true);
        }
        #pragma unroll
        for (int q = 0; q < 8; ++q) s[q] = ns[q];
        j = nj;
    }
    for (; j < e; ++j) {
        unsigned t = t1q[(size_t)csr[j] * 64 + lane];
        acc01 += __builtin_amdgcn_cvt_pk_f32_fp8((int)t, false);
        acc23 += __builtin_amdgcn_cvt_pk_f32_fp8((int)t, true);
    }
    float dv = dinv[v];
    int pk = __builtin_amdgcn_cvt_pk_fp8_f32(acc01[0] * dv, acc01[1] * dv, 0, false);
    pk = __builtin_amdgcn_cvt_pk_fp8_f32(acc23[0] * dv, acc23[1] * dv, pk, true);
    out[(size_t)v * 64 + lane] = (unsigned)pk;
}

// t2 fp8 64-B rows: 4 lane-groups of 16, each gathers a different edge; fused lsm
__global__ __launch_bounds__(256) void agg47_lsm_kernel(
    const unsigned* __restrict__ t2q, const int* __restrict__ offs,
    const int* __restrict__ csr, const float* __restrict__ dinv,
    const float* __restrict__ bias, float* __restrict__ out)
{
    int lane = threadIdx.x & 63;
    int grp = lane >> 4;          // 0..3
    int gl = lane & 15;           // u32 slot (4 cols)
    int v = blockIdx.x * 4 + (threadIdx.x >> 6);
    f32x2 a01 = {0.f, 0.f}, a23 = {0.f, 0.f};
    if (grp == 0) {
        unsigned u = t2q[(size_t)v * 16 + gl];        // self loop
        a01 += __builtin_amdgcn_cvt_pk_f32_fp8((int)u, false);
        a23 += __builtin_amdgcn_cvt_pk_f32_fp8((int)u, true);
    }
    int b = offs[v], e = offs[v + 1];
    int j = b + grp;
    int s[8];
    bool have = (j + 28 < e);
    if (have) {
        #pragma unroll
        for (int q = 0; q < 8; ++q) s[q] = csr[j + 4 * q];
    }
    while (have) {
        int nj = j + 32;
        bool nhave = (nj + 28 < e);
        int ns[8];
        if (nhave) {
            #pragma unroll
            for (int q = 0; q < 8; ++q) ns[q] = csr[nj + 4 * q];
        }
        #pragma unroll
        for (int q = 0; q < 8; ++q) {
            unsigned t = t2q[(size_t)s[q] * 16 + gl];
            a01 += __builtin_amdgcn_cvt_pk_f32_fp8((int)t, false);
            a23 += __builtin_amdgcn_cvt_pk_f32_fp8((int)t, true);
        }
        #pragma unroll
        for (int q = 0; q < 8; ++q) s[q] = ns[q];
        j = nj; have = nhave;
    }
    for (; j < e; j += 4) {
        unsigned t = t2q[(size_t)csr[j] * 16 + gl];
        a01 += __builtin_amdgcn_cvt_pk_f32_fp8((int)t, false);
        a23 += __builtin_amdgcn_cvt_pk_f32_fp8((int)t, true);
    }
    #pragma unroll
    for (int o = 16; o <= 32; o <<= 1) {
        a01[0] += __shfl_xor(a01[0], o, 64);
        a01[1] += __shfl_xor(a01[1], o, 64);
        a23[0] += __shfl_xor(a23[0], o, 64);
        a23[1] += __shfl_xor(a23[1], o, 64);
    }
    float dv = dinv[v];
    float vals[4] = {a01[0], a01[1], a23[0], a23[1]};
    float vv[4];
    #pragma unroll
    for (int k = 0; k < 4; ++k) {
        int c = 4 * gl + k;
        vv[k] = (c < CO) ? fmaf(vals[k], dv, bias[c]) : -1e30f;
    }
    float m = fmaxf(fmaxf(vv[0], vv[1]), fmaxf(vv[2], vv[3]));
    #pragma unroll
    for (int o = 8; o > 0; o >>= 1) m = fmaxf(m, __shfl_xor(m, o, 64));
    float sum = 0.f;
    #pragma unroll
    for (int k = 0; k < 4; ++k) sum += (vv[k] > -1e29f) ? expf(vv[k] - m) : 0.f;
    #pragma unroll
    for (int o = 8; o > 0; o >>= 1) sum += __shfl_xor(sum, o, 64);
    float lse = m + logf(sum);
    if (grp == 0) {
        #pragma unroll
        for (int k = 0; k < 4; ++k) {
            int c = 4 * gl + k;
            if (c < CO) out[(size_t)v * CO + c] = vv[k] - lse;
        }
    }
}

// ---------------- wide MFMA GEMM: BM=128, BN=256 (full), BK=64, 1 block/row-panel ----
// 4 waves 2x2; wave tile 64x128 = 4x8 frags. acc[4][8].

#define LDS_PAD 8

template<int K, bool XFORM, bool EPI_DINV, bool OUT8, bool BNSTAT>
__global__ __launch_bounds__(256) void mfma_gemm_wide(
    const _Float16* __restrict__ A, int lda,
    const _Float16* __restrict__ Wt,
    const float* __restrict__ ss, const float* __restrict__ dinv,
    void* __restrict__ outp, int ldo, float* __restrict__ part8)
{
    __shared__ __align__(16) _Float16 As[128][64 + LDS_PAD];
    __shared__ __align__(16) _Float16 Bs[256][64 + LDS_PAD];
    __shared__ float SS[2 * K];
    __shared__ float cstat[512];
    const int row0 = blockIdx.x * 128;
    const int tid = threadIdx.x;
    if (XFORM) {
        for (int i = tid; i < 2 * K; i += 256) SS[i] = ss[i];
    }
    if (BNSTAT) { cstat[tid] = 0.f; cstat[tid + 256] = 0.f; }
    const int lane = tid & 63;
    const int wv = tid >> 6;
    const int wr = wv >> 1, wc = wv & 1;
    const int fr = lane & 15;
    const int kb = (lane >> 4) * 8;

    f32x4 acc[4][8];
    #pragma unroll
    for (int m = 0; m < 4; ++m)
        #pragma unroll
        for (int n = 0; n < 8; ++n)
            acc[m][n] = (f32x4){0.f, 0.f, 0.f, 0.f};

    if (XFORM || BNSTAT) __syncthreads();

    for (int k0 = 0; k0 < K; k0 += 64) {
        #pragma unroll
        for (int p = 0; p < 4; ++p) {
            int c = p * 256 + tid;
            int m = c >> 3, kk = (c & 7) * 8;
            int r = row0 + m;
            h8 av = {};
            if (r < NN) av = *(const h8*)&A[(size_t)r * lda + k0 + kk];
            if (XFORM) {
                #pragma unroll
                for (int j = 0; j < 8; ++j) {
                    float a = (float)av[j];
                    a = fmaxf(fmaf(a, SS[k0 + kk + j], SS[K + k0 + kk + j]), 0.0f);
                    av[j] = (_Float16)a;
                }
            }
            *(h8*)&As[m][kk] = av;
        }
        #pragma unroll
        for (int p = 0; p < 8; ++p) {
            int c = p * 256 + tid;
            int n = c >> 3, kk = (c & 7) * 8;
            h8 bv = *(const h8*)&Wt[(size_t)n * K + k0 + kk];
            *(h8*)&Bs[n][kk] = bv;
        }
        __syncthreads();
        #pragma unroll
        for (int ks = 0; ks < 2; ++ks) {
            h8 a[4], b[8];
            #pragma unroll
            for (int m = 0; m < 4; ++m)
                a[m] = *(const h8*)&As[wr * 64 + m * 16 + fr][ks * 32 + kb];
            #pragma unroll
            for (int n = 0; n < 8; ++n)
                b[n] = *(const h8*)&Bs[wc * 128 + n * 16 + fr][ks * 32 + kb];
            #pragma unroll
            for (int m = 0; m < 4; ++m)
                #pragma unroll
                for (int n = 0; n < 8; ++n)
                    acc[m][n] = __builtin_amdgcn_mfma_f32_16x16x32_f16(a[m], b[n], acc[m][n], 0, 0, 0);
        }
        __syncthreads();
    }

    const int fq = lane >> 4;
    if (OUT8) {
        // stage fp8 tile 128x256 (32KB) in Bs region, then coalesced 16B stores
        unsigned char* stg = (unsigned char*)&Bs[0][0];
        #pragma unroll
        for (int m = 0; m < 4; ++m) {
            #pragma unroll
            for (int j = 0; j < 4; ++j) {
                int rr = wr * 64 + m * 16 + fq * 4 + j;
                int r = row0 + rr;
                float dv = (EPI_DINV && r < NN) ? dinv[r] : 1.0f;
                #pragma unroll
                for (int n = 0; n < 8; n += 2) {
                    int cc0 = wc * 128 + n * 16 + fr;
                    float v0 = acc[m][n][j] * dv;
                    float v1 = acc[m][n + 1][j] * dv;
                    int pk = __builtin_amdgcn_cvt_pk_fp8_f32(v0, v1, 0, false);
                    stg[rr * 256 + cc0] = (unsigned char)(pk & 0xFF);
                    stg[rr * 256 + cc0 + 16] = (unsigned char)((pk >> 8) & 0xFF);
                }
            }
        }
        __syncthreads();
        #pragma unroll
        for (int p = 0; p < 8; ++p) {
            int idx = p * 256 + tid;
            int rr = idx >> 4;
            int cc = (idx & 15) * 16;
            int r = row0 + rr;
            if (r < NN)
                *(u32x4*)&((unsigned char*)outp)[(size_t)r * ldo + cc] =
                    *(u32x4*)&stg[rr * 256 + cc];
        }
    } else {
        float ps[8] = {}, pq[8] = {};
        #pragma unroll
        for (int m = 0; m < 4; ++m) {
            #pragma unroll
            for (int j = 0; j < 4; ++j) {
                int r = row0 + wr * 64 + m * 16 + fq * 4 + j;
                if (r >= NN) continue;
                float dv = EPI_DINV ? dinv[r] : 1.0f;
                #pragma unroll
                for (int n = 0; n < 8; ++n) {
                    int c = wc * 128 + n * 16 + fr;
                    float val = acc[m][n][j] * dv;
                    ((_Float16*)outp)[(size_t)r * ldo + c] = (_Float16)val;
                    if (BNSTAT) { ps[n] += val; pq[n] += val * val; }
                }
            }
        }
        if (BNSTAT) {
            #pragma unroll
            for (int n = 0; n < 8; ++n) {
                int cc = wc * 128 + n * 16 + fr;
                atomicAdd(&cstat[cc], ps[n]);
                atomicAdd(&cstat[256 + cc], pq[n]);
            }
            __syncthreads();
            int rep = (blockIdx.x & 7) * 512;
            atomicAdd(&part8[rep + tid], cstat[tid]);
            atomicAdd(&part8[rep + 256 + tid], cstat[256 + tid]);
        }
    }
}

// ---------------- layer-2 GEMM: fp8 A (BN+ReLU on load), fp8 out 64-col rows -----

__global__ __launch_bounds__(256) void mfma_gemm2_kernel(
    const unsigned* __restrict__ Aq,
    const _Float16* __restrict__ Wt,
    const float* __restrict__ ss, const float* __restrict__ dinv,
    unsigned char* __restrict__ t2q)
{
    __shared__ __align__(16) _Float16 As[128][32 + LDS_PAD];
    __shared__ __align__(16) _Float16 Bs[64][32 + LDS_PAD];
    __shared__ float SS[2 * HD];
    const int row0 = blockIdx.x * 128;
    const int tid = threadIdx.x;
    for (int i = tid; i < 2 * HD; i += 256) SS[i] = ss[i];
    const int lane = tid & 63;
    const int wv = tid >> 6;
    const int wr = wv >> 1, wc = wv & 1;
    const int fr = lane & 15;
    const int kb = (lane >> 4) * 8;

    f32x4 acc[4][2];
    #pragma unroll
    for (int m = 0; m < 4; ++m)
        #pragma unroll
        for (int n = 0; n < 2; ++n)
            acc[m][n] = (f32x4){0.f, 0.f, 0.f, 0.f};

    __syncthreads();

    for (int k0 = 0; k0 < HD; k0 += 32) {
        #pragma unroll
        for (int p = 0; p < 2; ++p) {
            int idx = (p * 256 + tid) * 8;
            int m = idx >> 5, kk = idx & 31;
            int r = row0 + m;
            float vals[8] = {};
            if (r < NN) {
                u32x2 u = *(const u32x2*)&Aq[(size_t)r * 64 + ((k0 + kk) >> 2)];
                f32x2 p0 = __builtin_amdgcn_cvt_pk_f32_fp8((int)u[0], false);
                f32x2 p1 = __builtin_amdgcn_cvt_pk_f32_fp8((int)u[0], true);
                f32x2 p2 = __builtin_amdgcn_cvt_pk_f32_fp8((int)u[1], false);
                f32x2 p3 = __builtin_amdgcn_cvt_pk_f32_fp8((int)u[1], true);
                vals[0] = p0[0]; vals[1] = p0[1]; vals[2] = p1[0]; vals[3] = p1[1];
                vals[4] = p2[0]; vals[5] = p2[1]; vals[6] = p3[0]; vals[7] = p3[1];
            }
            h8 av;
            #pragma unroll
            for (int j = 0; j < 8; ++j) {
                float a = fmaxf(fmaf(vals[j], SS[k0 + kk + j], SS[HD + k0 + kk + j]), 0.0f);
                av[j] = (_Float16)a;
            }
            *(h8*)&As[m][kk] = av;
        }
        {
            int idx = tid * 8;
            int n = idx >> 5, kk = idx & 31;
            h8 bv = *(const h8*)&Wt[(size_t)n * HD + k0 + kk];
            *(h8*)&Bs[n][kk] = bv;
        }
        __syncthreads();
        h8 a[4], b[2];
        #pragma unroll
        for (int m = 0; m < 4; ++m)
            a[m] = *(const h8*)&As[wr * 64 + m * 16 + fr][kb];
        #pragma unroll
        for (int n = 0; n < 2; ++n)
            b[n] = *(const h8*)&Bs[wc * 32 + n * 16 + fr][kb];
        #pragma unroll
        for (int m = 0; m < 4; ++m)
            #pragma unroll
            for (int n = 0; n < 2; ++n)
                acc[m][n] = __builtin_amdgcn_mfma_f32_16x16x32_f16(a[m], b[n], acc[m][n], 0, 0, 0);
        __syncthreads();
    }

    const int fq = lane >> 4;
    unsigned char* stg = (unsigned char*)&As[0][0];
    #pragma unroll
    for (int m = 0; m < 4; ++m) {
        #pragma unroll
        for (int j = 0; j < 4; ++j) {
            int rr = wr * 64 + m * 16 + fq * 4 + j;
            int r = row0 + rr;
            float dv = (r < NN) ? dinv[r] : 1.0f;
            int cc0 = wc * 32 + fr;
            float v0 = acc[m][0][j] * dv;
            float v1 = acc[m][1][j] * dv;
            int pk = __builtin_amdgcn_cvt_pk_fp8_f32(v0, v1, 0, false);
            stg[rr * 64 + cc0] = (unsigned char)(pk & 0xFF);
            stg[rr * 64 + cc0 + 16] = (unsigned char)((pk >> 8) & 0xFF);
        }
    }
    __syncthreads();
    #pragma unroll
    for (int p = 0; p < 2; ++p) {
        int idx = p * 256 + tid;
        int rr = idx >> 2;
        int cc = (idx & 3) * 16;
        int r = row0 + rr;
        if (r < NN)
            *(u32x4*)&t2q[(size_t)r * 64 + cc] = *(u32x4*)&stg[rr * 64 + cc];
    }
}

// ---------------- BN stats ----------------

__global__ void bn_finalize8_kernel(const float* __restrict__ part8,
                                    const float* __restrict__ g,
                                    const float* __restrict__ be,
                                    float* __restrict__ ss) {
    int t = threadIdx.x;
    float s1 = 0.f, s2 = 0.f;
    #pragma unroll
    for (int x = 0; x < 8; ++x) {
        s1 += part8[x * 512 + t];
        s2 += part8[x * 512 + 256 + t];
    }
    float mean = s1 * (1.0f / NN);
    float var = s2 * (1.0f / NN) - mean * mean;
    float sc = g[t] * rsqrtf(var + 1e-5f);
    ss[t] = sc;
    ss[HD + t] = be[t] - mean * sc;
}

__global__ __launch_bounds__(256) void bn_part8_kernel(const unsigned* __restrict__ h,
                                                       float* __restrict__ part) {
    int tid = threadIdx.x;
    int fg = tid & 63;
    int rg = tid >> 6;
    float s1[4] = {}, s2[4] = {};
    for (int r = blockIdx.x * 4 + rg; r < NN; r += 4096) {
        unsigned u = h[(size_t)r * 64 + fg];
        f32x2 a = __builtin_amdgcn_cvt_pk_f32_fp8((int)u, false);
        f32x2 b = __builtin_amdgcn_cvt_pk_f32_fp8((int)u, true);
        float f0 = a[0], f1 = a[1], f2 = b[0], f3 = b[1];
        s1[0] += f0; s2[0] += f0 * f0;
        s1[1] += f1; s2[1] += f1 * f1;
        s1[2] += f2; s2[2] += f2 * f2;
        s1[3] += f3; s2[3] += f3 * f3;
    }
    __shared__ float sm[256][8];
    #pragma unroll
    for (int j = 0; j < 4; ++j) { sm[tid][j] = s1[j]; sm[tid][4 + j] = s2[j]; }
    __syncthreads();
    if (tid < 64) {
        float o1[4] = {}, o2[4] = {};
        #pragma unroll
        for (int r = 0; r < 4; ++r)
            #pragma unroll
            for (int j = 0; j < 4; ++j) {
                o1[j] += sm[r * 64 + tid][j];
                o2[j] += sm[r * 64 + tid][4 + j];
            }
        #pragma unroll
        for (int j = 0; j < 4; ++j) {
            part[(size_t)blockIdx.x * 512 + tid * 4 + j] = o1[j];
            part[(size_t)blockIdx.x * 512 + 256 + tid * 4 + j] = o2[j];
        }
    }
}

__global__ __launch_bounds__(256) void bn_reduce_kernel(const float* __restrict__ part,
                                                        const float* __restrict__ g,
                                                        const float* __restrict__ be,
                                                        float* __restrict__ ss) {
    int f = blockIdx.x * 32 + (threadIdx.x & 31);
    int c = threadIdx.x >> 5;
    float s1 = 0.f, s2 = 0.f;
    for (int b = c; b < 1024; b += 8) {
        s1 += part[(size_t)b * 512 + f];
        s2 += part[(size_t)b * 512 + 256 + f];
    }
    __shared__ float m1[8][32], m2[8][32];
    m1[c][threadIdx.x & 31] = s1; m2[c][threadIdx.x & 31] = s2;
    __syncthreads();
    if (threadIdx.x < 32) {
        float t1 = 0.f, t2 = 0.f;
        #pragma unroll
        for (int q = 0; q < 8; ++q) { t1 += m1[q][threadIdx.x]; t2 += m2[q][threadIdx.x]; }
        float mean = t1 * (1.0f / NN);
        float var = t2 * (1.0f / NN) - mean * mean;
        float sc = g[f] * rsqrtf(var + 1e-5f);
        ss[f] = sc;
        ss[HD + f] = be[f] - mean * sc;
    }
}

// ---------------- launch ----------------

extern "C" void kernel_launch(void* const* d_in, const int* in_sizes, int n_in,
                              void* d_out, int out_size, void* d_ws, size_t ws_size,
                              hipStream_t stream) {
    const float* x   = (const float*)d_in[0];
    const int*   ei  = (const int*)d_in[1];
    const float* W0  = (const float*)d_in[3];
    const float* g0  = (const float*)d_in[5];
    const float* be0 = (const float*)d_in[6];
    const float* W1  = (const float*)d_in[7];
    const float* g1  = (const float*)d_in[9];
    const float* be1 = (const float*)d_in[10];
    const float* W2  = (const float*)d_in[11];
    const float* b2  = (const float*)d_in[12];
    float* out = (float*)d_out;

    const int* src = ei;            // edge_index[0]
    const int* dst = ei + NE;       // edge_index[1]

    const size_t S = 51200000;                        // 100000*256*2 bytes
    char* ws = (char*)d_ws;
    unsigned*       xq  = (unsigned*)ws;
    unsigned*       t1q = (unsigned*)ws;
    unsigned char*  t2q = (unsigned char*)ws;
    _Float16*       a0  = (_Float16*)(ws + 25600000); // [NN][128] fp16 (25.6MB)
    _Float16*       S2  = (_Float16*)(ws + S);        // h0 (fp16) / h1q (fp8) slot
    unsigned*       h1q = (unsigned*)(ws + S);
    char* base2 = ws + 2 * S;
    int*   csr  = (int*)  (base2);                    // 12.8MB
    int*   offs = (int*)  (base2 + 12800000);
    float* dinv = (float*)(base2 + 13200064);
    float* ssb  = (float*)(base2 + 13602112);
    int*   btot = (int*)  (base2 + 13604160);
    int*   bbase= (int*)  (base2 + 13605184);
    _Float16* wt0 = (_Float16*)(base2 + 13608320);    // [256][128]
    _Float16* wt1 = (_Float16*)(base2 + 13673856);    // [256][256]
    _Float16* wt2 = (_Float16*)(base2 + 13804928);    // [64][256]
    int*   hist = (int*)  (base2 + 13837696);         // NBKT*G ints
    int*   epk  = (int*)  (base2 + 14640576);         // NE ints = 12.8MB
    float* part = (float*)(base2 + 27440576);         // 1024*512 floats = 2MB
    float* part8= (float*)(base2 + 29537728);         // 8*512 floats = 16KB

    // CSR build: bucketed counting sort
    hist_kernel<<<G, 256, 0, stream>>>(dst, hist);
    rowscan_kernel<<<NBKT, 256, 0, stream>>>(hist, btot);
    totscan_kernel<<<1, 256, 0, stream>>>(btot, bbase);
    scatter_kernel<<<G, 256, 0, stream>>>(src, dst, hist, bbase, epk);
    bucket_fill_kernel<<<NBKT, 256, 0, stream>>>(bbase, epk, csr, offs, dinv);

    // weights -> fp16 transposed (one launch)
    wtrans_all_kernel<<<448, 256, 0, stream>>>(W0, W1, W2, wt0, wt1, wt2);

    const int MB = (NN + 127) / 128;   // 782

    // Layer 0: a0 = D^-1/2 (A+I) D^-1/2 x (fp8 gather); h0 = a0 @ W0 (+fused BN stats)
    hipMemsetAsync(part8, 0, 8 * 512 * sizeof(float), stream);
    conv_x_kernel<<<(NN * FIN / 4 + 255) / 256, 256, 0, stream>>>(x, dinv, xq);
    agg128_kernel<<<NN / 4, 256, 0, stream>>>(xq, offs, csr, dinv, a0);
    mfma_gemm_wide<FIN, false, false, false, true><<<MB, 256, 0, stream>>>(
        a0, FIN, wt0, nullptr, dinv, S2, HD, part8);            // h0 -> S2 (fp16)
    bn_finalize8_kernel<<<1, HD, 0, stream>>>(part8, g0, be0, ssb);

    // Layer 1: t1 = dinv * (relu(bn(h0)) @ W1) -> fp8; h1 = dinv*(A+I)t1 -> fp8
    mfma_gemm_wide<HD, true, true, true, false><<<MB, 256, 0, stream>>>(
        S2, HD, wt1, ssb, dinv, t1q, HD, nullptr);              // t1q -> slot A
    agg256_kernel<<<NN / 4, 256, 0, stream>>>(t1q, offs, csr, dinv, h1q);  // h1q -> S2

    bn_part8_kernel<<<1024, 256, 0, stream>>>(h1q, part);
    bn_reduce_kernel<<<8, 256, 0, stream>>>(part, g1, be1, ssb);

    // Layer 2: t2 = dinv * (relu(bn(h1)) @ W2) -> fp8 64B rows; agg + log_softmax
    mfma_gemm2_kernel<<<MB, 256, 0, stream>>>(h1q, wt2, ssb, dinv, t2q);
    agg47_lsm_kernel<<<NN / 4, 256, 0, stream>>>((const unsigned*)t2q, offs, csr, dinv, b2, out);
}

// Round 16
// 545.661 us; speedup vs baseline: 1.0921x; 1.0921x over previous
//
#include <hip/hip_runtime.h>
#include <hip/hip_fp8.h>
#include <math.h>

#define NN 100000
#define NE 3200000
#define FIN 128
#define HD 256
#define CO 47
#define NBKT 196   // buckets of 512 nodes: dst>>9
#define G 1024     // partition blocks
#define CHUNK 3125 // NE / G exactly

typedef _Float16 h2 __attribute__((ext_vector_type(2)));
typedef _Float16 h4 __attribute__((ext_vector_type(4)));
typedef _Float16 h8 __attribute__((ext_vector_type(8)));
typedef float f32x2 __attribute__((ext_vector_type(2)));
typedef float f32x4 __attribute__((ext_vector_type(4)));
typedef unsigned int u32x2 __attribute__((ext_vector_type(2)));
typedef unsigned int u32x4 __attribute__((ext_vector_type(4)));

// ---------------- CSR build via bucketed counting sort ----------------

__global__ __launch_bounds__(256) void hist_kernel(const int* __restrict__ dst,
                                                   int* __restrict__ hist) {
    __shared__ int h[NBKT];
    int tid = threadIdx.x;
    for (int i = tid; i < NBKT; i += 256) h[i] = 0;
    __syncthreads();
    int base = blockIdx.x * CHUNK;
    for (int i = tid; i < CHUNK; i += 256)
        atomicAdd(&h[dst[base + i] >> 9], 1);
    __syncthreads();
    for (int i = tid; i < NBKT; i += 256) hist[i * G + blockIdx.x] = h[i];
}

__global__ __launch_bounds__(256) void rowscan_kernel(int* __restrict__ hist,
                                                      int* __restrict__ btot) {
    __shared__ int sums[256];
    int b = blockIdx.x, t = threadIdx.x;
    int base = b * G + t * 4;
    int4 v = *(int4*)&hist[base];
    int i0 = v.x, i1 = i0 + v.y, i2 = i1 + v.z, i3 = i2 + v.w;
    sums[t] = i3;
    __syncthreads();
    #pragma unroll
    for (int off = 1; off < 256; off <<= 1) {
        int u = (t >= off) ? sums[t - off] : 0;
        __syncthreads();
        sums[t] += u;
        __syncthreads();
    }
    int excl = sums[t] - i3;
    hist[base] = excl;
    hist[base + 1] = excl + i0;
    hist[base + 2] = excl + i1;
    hist[base + 3] = excl + i2;
    if (t == 255) btot[b] = sums[255];
}

__global__ void totscan_kernel(const int* __restrict__ btot, int* __restrict__ bbase) {
    __shared__ int tmp[256];
    int t = threadIdx.x;
    int v = (t < NBKT) ? btot[t] : 0;
    tmp[t] = v;
    __syncthreads();
    #pragma unroll
    for (int off = 1; off < 256; off <<= 1) {
        int u = (t >= off) ? tmp[t - off] : 0;
        __syncthreads();
        tmp[t] += u;
        __syncthreads();
    }
    if (t < NBKT) bbase[t] = tmp[t] - v;
    if (t == NBKT - 1) bbase[NBKT] = tmp[t];
}

__global__ __launch_bounds__(256) void scatter_kernel(const int* __restrict__ src,
                                                      const int* __restrict__ dst,
                                                      const int* __restrict__ hscan,
                                                      const int* __restrict__ bbase,
                                                      int* __restrict__ epk) {
    __shared__ int cur[NBKT];
    int tid = threadIdx.x;
    for (int i = tid; i < NBKT; i += 256)
        cur[i] = hscan[i * G + blockIdx.x] + bbase[i];
    __syncthreads();
    int base = blockIdx.x * CHUNK;
    for (int i = tid; i < CHUNK; i += 256) {
        int e = base + i;
        int d = dst[e];
        int slot = atomicAdd(&cur[d >> 9], 1);
        epk[slot] = ((d & 511) << 17) | src[e];
    }
}

__global__ __launch_bounds__(256) void bucket_fill_kernel(
    const int* __restrict__ bbase, const int* __restrict__ epk,
    int* __restrict__ csr, int* __restrict__ offs, float* __restrict__ dinv)
{
    __shared__ int deg[512], cur[512], a0[512], a1[512];
    int tid = threadIdx.x, b = blockIdx.x;
    int ebeg = bbase[b], eend = bbase[b + 1];
    deg[tid] = 0; deg[tid + 256] = 0;
    __syncthreads();
    for (int e = ebeg + tid; e < eend; e += 256)
        atomicAdd(&deg[((unsigned)epk[e]) >> 17], 1);
    __syncthreads();
    a0[tid] = deg[tid]; a0[tid + 256] = deg[tid + 256];
    __syncthreads();
    int* pin = a0; int* pout = a1;
    for (int off = 1; off < 512; off <<= 1) {
        #pragma unroll
        for (int q = 0; q < 2; ++q) {
            int p = tid + q * 256;
            pout[p] = pin[p] + ((p >= off) ? pin[p - off] : 0);
        }
        __syncthreads();
        int* t = pin; pin = pout; pout = t;
    }
    #pragma unroll
    for (int q = 0; q < 2; ++q) {
        int i = tid + q * 256;
        int excl = pin[i] - deg[i];
        cur[i] = excl;
        int node = b * 512 + i;
        if (node < NN) {
            offs[node] = ebeg + excl;
            dinv[node] = rsqrtf((float)deg[i] + 1.0f);
        }
    }
    if (b == 0 && tid == 0) offs[NN] = NE;
    __syncthreads();
    for (int e = ebeg + tid; e < eend; e += 256) {
        int pk = epk[e];
        int p = atomicAdd(&cur[((unsigned)pk) >> 17], 1);
        csr[ebeg + p] = pk & 0x1FFFF;
    }
}

// ---------------- weight convert (all three, one launch) ----------------

__global__ void wtrans_all_kernel(const float* __restrict__ W0,
                                  const float* __restrict__ W1,
                                  const float* __restrict__ W2,
                                  _Float16* __restrict__ wt0,
                                  _Float16* __restrict__ wt1,
                                  _Float16* __restrict__ wt2) {
    int i = blockIdx.x * 256 + threadIdx.x;
    if (i < 256 * 128) {                       // wt0[n][k] = W0[k][n], [256][128]
        int n = i >> 7, k = i & 127;
        wt0[i] = (_Float16)W0[k * 256 + n];
    } else if (i < 256 * 128 + 256 * 256) {    // wt1[n][k] = W1[k][n], [256][256]
        int t = i - 256 * 128;
        int n = t >> 8, k = t & 255;
        wt1[t] = (_Float16)W1[k * 256 + n];
    } else if (i < 256 * 128 + 256 * 256 + 64 * 256) {  // wt2[n][k], n>=CO zero
        int t = i - 256 * 128 - 256 * 256;
        int n = t >> 8, k = t & 255;
        wt2[t] = (_Float16)((n < CO) ? W2[k * CO + n] : 0.0f);
    }
}

// ---------------- x -> fp8 e4m3 (OCP) via HW cvt, pre-scaled by dinv ----------------

__global__ void conv_x_kernel(const float* __restrict__ x, const float* __restrict__ dinv,
                              unsigned* __restrict__ xq) {
    int i = blockIdx.x * 256 + threadIdx.x;     // over NN*FIN/4
    if (i >= NN * FIN / 4) return;
    int r = i >> 5;
    float4 v = ((const float4*)x)[i];
    float dv = dinv[r];
    int u = __builtin_amdgcn_cvt_pk_fp8_f32(v.x * dv, v.y * dv, 0, false);
    u = __builtin_amdgcn_cvt_pk_fp8_f32(v.z * dv, v.w * dv, u, true);
    xq[i] = (unsigned)u;
}

// ---------------- aggregation (wave per node, atomic-free, HW fp8 decode) --------
// agg128: 2 lane-groups of 32; each group gathers a different edge (32 x u32 = 128B row).

__global__ __launch_bounds__(256) void agg128_kernel(
    const unsigned* __restrict__ xq, const int* __restrict__ offs,
    const int* __restrict__ csr, const float* __restrict__ dinv,
    _Float16* __restrict__ out)
{
    int lane = threadIdx.x & 63;
    int grp = lane >> 5;          // 0..1
    int gl = lane & 31;           // u32 slot within row (4 cols)
    int v = blockIdx.x * 4 + (threadIdx.x >> 6);
    f32x2 a01 = {0.f, 0.f}, a23 = {0.f, 0.f};
    if (grp == 0) {
        unsigned sv = xq[(size_t)v * 32 + gl];        // self loop
        a01 += __builtin_amdgcn_cvt_pk_f32_fp8((int)sv, false);
        a23 += __builtin_amdgcn_cvt_pk_f32_fp8((int)sv, true);
    }
    int b = offs[v], e = offs[v + 1];
    int j = b + grp;              // group g takes edges b+g, b+g+2, ...
    int s[8];
    bool have = (j + 14 < e);
    if (have) {
        #pragma unroll
        for (int q = 0; q < 8; ++q) s[q] = csr[j + 2 * q];
    }
    while (have) {
        int nj = j + 16;
        bool nhave = (nj + 14 < e);
        int ns[8];
        if (nhave) {
            #pragma unroll
            for (int q = 0; q < 8; ++q) ns[q] = csr[nj + 2 * q];
        }
        #pragma unroll
        for (int q = 0; q < 8; ++q) {
            unsigned t = xq[(size_t)s[q] * 32 + gl];
            a01 += __builtin_amdgcn_cvt_pk_f32_fp8((int)t, false);
            a23 += __builtin_amdgcn_cvt_pk_f32_fp8((int)t, true);
        }
        #pragma unroll
        for (int q = 0; q < 8; ++q) s[q] = ns[q];
        j = nj; have = nhave;
    }
    for (; j < e; j += 2) {
        unsigned t = xq[(size_t)csr[j] * 32 + gl];
        a01 += __builtin_amdgcn_cvt_pk_f32_fp8((int)t, false);
        a23 += __builtin_amdgcn_cvt_pk_f32_fp8((int)t, true);
    }
    // cross-group reduce (lane ^ 32 holds the other half of the edge list)
    a01[0] += __shfl_xor(a01[0], 32, 64);
    a01[1] += __shfl_xor(a01[1], 32, 64);
    a23[0] += __shfl_xor(a23[0], 32, 64);
    a23[1] += __shfl_xor(a23[1], 32, 64);
    if (grp == 0) {
        float dv = dinv[v];
        h4 o; o[0] = (_Float16)(a01[0] * dv); o[1] = (_Float16)(a01[1] * dv);
        o[2] = (_Float16)(a23[0] * dv); o[3] = (_Float16)(a23[1] * dv);
        ((h4*)out)[(size_t)v * 32 + gl] = o;
    }
}

// t1 fp8 gather -> h1 written as fp8 (packed u32); proven 8-deep full-wave config
__global__ __launch_bounds__(256) void agg256_kernel(
    const unsigned* __restrict__ t1q, const int* __restrict__ offs,
    const int* __restrict__ csr, const float* __restrict__ dinv,
    unsigned* __restrict__ out)
{
    int lane = threadIdx.x & 63;
    int v = blockIdx.x * 4 + (threadIdx.x >> 6);
    unsigned sv = t1q[(size_t)v * 64 + lane];   // 4 fp8 per lane
    f32x2 acc01 = __builtin_amdgcn_cvt_pk_f32_fp8((int)sv, false);
    f32x2 acc23 = __builtin_amdgcn_cvt_pk_f32_fp8((int)sv, true);
    int b = offs[v], e = offs[v + 1], j = b;
    int s[8];
    if (j + 8 <= e) {
        #pragma unroll
        for (int q = 0; q < 8; ++q) s[q] = csr[j + q];
    }
    for (; j + 8 <= e; ) {
        int nj = j + 8;
        int ns[8];
        if (nj + 8 <= e) {
            #pragma unroll
            for (int q = 0; q < 8; ++q) ns[q] = csr[nj + q];
        }
        #pragma unroll
        for (int q = 0; q < 8; ++q) {
            unsigned t = t1q[(size_t)s[q] * 64 + lane];
            acc01 += __builtin_amdgcn_cvt_pk_f32_fp8((int)t, false);
            acc23 += __builtin_amdgcn_cvt_pk_f32_fp8((int)t, true);
        }
        #pragma unroll
        for (int q = 0; q < 8; ++q) s[q] = ns[q];
        j = nj;
    }
    for (; j < e; ++j) {
        unsigned t = t1q[(size_t)csr[j] * 64 + lane];
        acc01 += __builtin_amdgcn_cvt_pk_f32_fp8((int)t, false);
        acc23 += __builtin_amdgcn_cvt_pk_f32_fp8((int)t, true);
    }
    float dv = dinv[v];
    int pk = __builtin_amdgcn_cvt_pk_fp8_f32(acc01[0] * dv, acc01[1] * dv, 0, false);
    pk = __builtin_amdgcn_cvt_pk_fp8_f32(acc23[0] * dv, acc23[1] * dv, pk, true);
    out[(size_t)v * 64 + lane] = (unsigned)pk;
}

// t2 fp8 64-B rows: 4 lane-groups of 16, each gathers a different edge; fused lsm
__global__ __launch_bounds__(256) void agg47_lsm_kernel(
    const unsigned* __restrict__ t2q, const int* __restrict__ offs,
    const int* __restrict__ csr, const float* __restrict__ dinv,
    const float* __restrict__ bias, float* __restrict__ out)
{
    int lane = threadIdx.x & 63;
    int grp = lane >> 4;          // 0..3
    int gl = lane & 15;           // u32 slot (4 cols)
    int v = blockIdx.x * 4 + (threadIdx.x >> 6);
    f32x2 a01 = {0.f, 0.f}, a23 = {0.f, 0.f};
    if (grp == 0) {
        unsigned u = t2q[(size_t)v * 16 + gl];        // self loop
        a01 += __builtin_amdgcn_cvt_pk_f32_fp8((int)u, false);
        a23 += __builtin_amdgcn_cvt_pk_f32_fp8((int)u, true);
    }
    int b = offs[v], e = offs[v + 1];
    int j = b + grp;              // group g takes edges b+g, b+g+4, ...
    int s[8];
    bool have = (j + 28 < e);
    if (have) {
        #pragma unroll
        for (int q = 0; q < 8; ++q) s[q] = csr[j + 4 * q];
    }
    while (have) {
        int nj = j + 32;
        bool nhave = (nj + 28 < e);
        int ns[8];
        if (nhave) {
            #pragma unroll
            for (int q = 0; q < 8; ++q) ns[q] = csr[nj + 4 * q];
        }
        #pragma unroll
        for (int q = 0; q < 8; ++q) {
            unsigned t = t2q[(size_t)s[q] * 16 + gl];
            a01 += __builtin_amdgcn_cvt_pk_f32_fp8((int)t, false);
            a23 += __builtin_amdgcn_cvt_pk_f32_fp8((int)t, true);
        }
        #pragma unroll
        for (int q = 0; q < 8; ++q) s[q] = ns[q];
        j = nj; have = nhave;
    }
    for (; j < e; j += 4) {
        unsigned t = t2q[(size_t)csr[j] * 16 + gl];
        a01 += __builtin_amdgcn_cvt_pk_f32_fp8((int)t, false);
        a23 += __builtin_amdgcn_cvt_pk_f32_fp8((int)t, true);
    }
    // cross-group reduce: lanes ^16 and ^32 hold the other edge sublists
    #pragma unroll
    for (int o = 16; o <= 32; o <<= 1) {
        a01[0] += __shfl_xor(a01[0], o, 64);
        a01[1] += __shfl_xor(a01[1], o, 64);
        a23[0] += __shfl_xor(a23[0], o, 64);
        a23[1] += __shfl_xor(a23[1], o, 64);
    }
    float dv = dinv[v];
    float vals[4] = {a01[0], a01[1], a23[0], a23[1]};
    float vv[4];
    #pragma unroll
    for (int k = 0; k < 4; ++k) {
        int c = 4 * gl + k;
        vv[k] = (c < CO) ? fmaf(vals[k], dv, bias[c]) : -1e30f;
    }
    float m = fmaxf(fmaxf(vv[0], vv[1]), fmaxf(vv[2], vv[3]));
    #pragma unroll
    for (int o = 8; o > 0; o >>= 1) m = fmaxf(m, __shfl_xor(m, o, 64));
    float sum = 0.f;
    #pragma unroll
    for (int k = 0; k < 4; ++k) sum += (vv[k] > -1e29f) ? expf(vv[k] - m) : 0.f;
    #pragma unroll
    for (int o = 8; o > 0; o >>= 1) sum += __shfl_xor(sum, o, 64);
    float lse = m + logf(sum);
    if (grp == 0) {
        #pragma unroll
        for (int k = 0; k < 4; ++k) {
            int c = 4 * gl + k;
            if (c < CO) out[(size_t)v * CO + c] = vv[k] - lse;
        }
    }
}

// ---------------- big MFMA GEMM: BM=128, BN=128, BK=64, paired-1D grid ----------

#define LDS_PAD 8

template<int K, bool XFORM, bool EPI_DINV, bool OUT8, bool BNSTAT>
__global__ __launch_bounds__(256) void mfma_gemm_big(
    const _Float16* __restrict__ A, int lda,
    const _Float16* __restrict__ Wt,
    const float* __restrict__ ss, const float* __restrict__ dinv,
    void* __restrict__ outp, int ldo, float* __restrict__ part8)
{
    __shared__ __align__(16) _Float16 As[128][64 + LDS_PAD];
    __shared__ __align__(16) _Float16 Bs[128][64 + LDS_PAD];
    __shared__ float SS[2 * K];
    __shared__ float cstat[256];
    const int row0 = (blockIdx.x >> 1) * 128;
    const int col0 = (blockIdx.x & 1) * 128;
    const int tid = threadIdx.x;
    if (XFORM) {
        for (int i = tid; i < 2 * K; i += 256) SS[i] = ss[i];
    }
    if (BNSTAT) cstat[tid] = 0.f;
    const int lane = tid & 63;
    const int wv = tid >> 6;
    const int wr = wv >> 1, wc = wv & 1;
    const int fr = lane & 15;
    const int kb = (lane >> 4) * 8;

    f32x4 acc[4][4];
    #pragma unroll
    for (int m = 0; m < 4; ++m)
        #pragma unroll
        for (int n = 0; n < 4; ++n)
            acc[m][n] = (f32x4){0.f, 0.f, 0.f, 0.f};

    if (XFORM || BNSTAT) __syncthreads();

    for (int k0 = 0; k0 < K; k0 += 64) {
        #pragma unroll
        for (int p = 0; p < 4; ++p) {
            int c = p * 256 + tid;
            int m = c >> 3, kk = (c & 7) * 8;
            int r = row0 + m;
            h8 av = {};
            if (r < NN) av = *(const h8*)&A[(size_t)r * lda + k0 + kk];
            if (XFORM) {
                #pragma unroll
                for (int j = 0; j < 8; ++j) {
                    float a = (float)av[j];
                    a = fmaxf(fmaf(a, SS[k0 + kk + j], SS[K + k0 + kk + j]), 0.0f);
                    av[j] = (_Float16)a;
                }
            }
            *(h8*)&As[m][kk] = av;
        }
        #pragma unroll
        for (int p = 0; p < 4; ++p) {
            int c = p * 256 + tid;
            int n = c >> 3, kk = (c & 7) * 8;
            h8 bv = *(const h8*)&Wt[(size_t)(col0 + n) * K + k0 + kk];
            *(h8*)&Bs[n][kk] = bv;
        }
        __syncthreads();
        #pragma unroll
        for (int ks = 0; ks < 2; ++ks) {
            h8 a[4], b[4];
            #pragma unroll
            for (int m = 0; m < 4; ++m)
                a[m] = *(const h8*)&As[wr * 64 + m * 16 + fr][ks * 32 + kb];
            #pragma unroll
            for (int n = 0; n < 4; ++n)
                b[n] = *(const h8*)&Bs[wc * 64 + n * 16 + fr][ks * 32 + kb];
            #pragma unroll
            for (int m = 0; m < 4; ++m)
                #pragma unroll
                for (int n = 0; n < 4; ++n)
                    acc[m][n] = __builtin_amdgcn_mfma_f32_16x16x32_f16(a[m], b[n], acc[m][n], 0, 0, 0);
        }
        __syncthreads();
    }

    const int fq = lane >> 4;
    if (OUT8) {
        unsigned char* stg = (unsigned char*)&As[0][0];
        #pragma unroll
        for (int m = 0; m < 4; ++m) {
            #pragma unroll
            for (int j = 0; j < 4; ++j) {
                int rr = wr * 64 + m * 16 + fq * 4 + j;
                int r = row0 + rr;
                float dv = (EPI_DINV && r < NN) ? dinv[r] : 1.0f;
                #pragma unroll
                for (int n = 0; n < 4; n += 2) {
                    int cc0 = wc * 64 + n * 16 + fr;
                    float v0 = acc[m][n][j] * dv;
                    float v1 = acc[m][n + 1][j] * dv;
                    int pk = __builtin_amdgcn_cvt_pk_fp8_f32(v0, v1, 0, false);
                    stg[rr * 128 + cc0] = (unsigned char)(pk & 0xFF);
                    stg[rr * 128 + cc0 + 16] = (unsigned char)((pk >> 8) & 0xFF);
                }
            }
        }
        __syncthreads();
        #pragma unroll
        for (int p = 0; p < 4; ++p) {
            int rr = p * 32 + (tid >> 3);
            int cc = (tid & 7) * 16;
            int r = row0 + rr;
            if (r < NN)
                *(u32x4*)&((unsigned char*)outp)[(size_t)r * ldo + col0 + cc] =
                    *(u32x4*)&stg[rr * 128 + cc];
        }
    } else {
        float ps[4] = {}, pq[4] = {};
        #pragma unroll
        for (int m = 0; m < 4; ++m) {
            #pragma unroll
            for (int j = 0; j < 4; ++j) {
                int r = row0 + wr * 64 + m * 16 + fq * 4 + j;
                if (r >= NN) continue;
                float dv = EPI_DINV ? dinv[r] : 1.0f;
                #pragma unroll
                for (int n = 0; n < 4; ++n) {
                    int c = col0 + wc * 64 + n * 16 + fr;
                    float val = acc[m][n][j] * dv;
                    ((_Float16*)outp)[(size_t)r * ldo + c] = (_Float16)val;
                    if (BNSTAT) { ps[n] += val; pq[n] += val * val; }
                }
            }
        }
        if (BNSTAT) {
            #pragma unroll
            for (int n = 0; n < 4; ++n) {
                int cc = wc * 64 + n * 16 + fr;
                atomicAdd(&cstat[cc], ps[n]);
                atomicAdd(&cstat[128 + cc], pq[n]);
            }
            __syncthreads();
            if (tid < 128) {
                int rep = (blockIdx.x & 7) * 512;
                atomicAdd(&part8[rep + col0 + tid], cstat[tid]);
                atomicAdd(&part8[rep + 256 + col0 + tid], cstat[128 + tid]);
            }
        }
    }
}

// ---------------- layer-2 GEMM: fp8 A (BN+ReLU on load), fp8 out 64-col rows -----

__global__ __launch_bounds__(256) void mfma_gemm2_kernel(
    const unsigned* __restrict__ Aq,
    const _Float16* __restrict__ Wt,
    const float* __restrict__ ss, const float* __restrict__ dinv,
    unsigned char* __restrict__ t2q)
{
    __shared__ __align__(16) _Float16 As[128][32 + LDS_PAD];
    __shared__ __align__(16) _Float16 Bs[64][32 + LDS_PAD];
    __shared__ float SS[2 * HD];
    const int row0 = blockIdx.x * 128;
    const int tid = threadIdx.x;
    for (int i = tid; i < 2 * HD; i += 256) SS[i] = ss[i];
    const int lane = tid & 63;
    const int wv = tid >> 6;
    const int wr = wv >> 1, wc = wv & 1;
    const int fr = lane & 15;
    const int kb = (lane >> 4) * 8;

    f32x4 acc[4][2];
    #pragma unroll
    for (int m = 0; m < 4; ++m)
        #pragma unroll
        for (int n = 0; n < 2; ++n)
            acc[m][n] = (f32x4){0.f, 0.f, 0.f, 0.f};

    __syncthreads();

    for (int k0 = 0; k0 < HD; k0 += 32) {
        #pragma unroll
        for (int p = 0; p < 2; ++p) {
            int idx = (p * 256 + tid) * 8;
            int m = idx >> 5, kk = idx & 31;
            int r = row0 + m;
            float vals[8] = {};
            if (r < NN) {
                u32x2 u = *(const u32x2*)&Aq[(size_t)r * 64 + ((k0 + kk) >> 2)];
                f32x2 p0 = __builtin_amdgcn_cvt_pk_f32_fp8((int)u[0], false);
                f32x2 p1 = __builtin_amdgcn_cvt_pk_f32_fp8((int)u[0], true);
                f32x2 p2 = __builtin_amdgcn_cvt_pk_f32_fp8((int)u[1], false);
                f32x2 p3 = __builtin_amdgcn_cvt_pk_f32_fp8((int)u[1], true);
                vals[0] = p0[0]; vals[1] = p0[1]; vals[2] = p1[0]; vals[3] = p1[1];
                vals[4] = p2[0]; vals[5] = p2[1]; vals[6] = p3[0]; vals[7] = p3[1];
            }
            h8 av;
            #pragma unroll
            for (int j = 0; j < 8; ++j) {
                float a = fmaxf(fmaf(vals[j], SS[k0 + kk + j], SS[HD + k0 + kk + j]), 0.0f);
                av[j] = (_Float16)a;
            }
            *(h8*)&As[m][kk] = av;
        }
        {
            int idx = tid * 8;
            int n = idx >> 5, kk = idx & 31;
            h8 bv = *(const h8*)&Wt[(size_t)n * HD + k0 + kk];
            *(h8*)&Bs[n][kk] = bv;
        }
        __syncthreads();
        h8 a[4], b[2];
        #pragma unroll
        for (int m = 0; m < 4; ++m)
            a[m] = *(const h8*)&As[wr * 64 + m * 16 + fr][kb];
        #pragma unroll
        for (int n = 0; n < 2; ++n)
            b[n] = *(const h8*)&Bs[wc * 32 + n * 16 + fr][kb];
        #pragma unroll
        for (int m = 0; m < 4; ++m)
            #pragma unroll
            for (int n = 0; n < 2; ++n)
                acc[m][n] = __builtin_amdgcn_mfma_f32_16x16x32_f16(a[m], b[n], acc[m][n], 0, 0, 0);
        __syncthreads();
    }

    const int fq = lane >> 4;
    unsigned char* stg = (unsigned char*)&As[0][0];
    #pragma unroll
    for (int m = 0; m < 4; ++m) {
        #pragma unroll
        for (int j = 0; j < 4; ++j) {
            int rr = wr * 64 + m * 16 + fq * 4 + j;
            int r = row0 + rr;
            float dv = (r < NN) ? dinv[r] : 1.0f;
            int cc0 = wc * 32 + fr;
            float v0 = acc[m][0][j] * dv;
            float v1 = acc[m][1][j] * dv;
            int pk = __builtin_amdgcn_cvt_pk_fp8_f32(v0, v1, 0, false);
            stg[rr * 64 + cc0] = (unsigned char)(pk & 0xFF);
            stg[rr * 64 + cc0 + 16] = (unsigned char)((pk >> 8) & 0xFF);
        }
    }
    __syncthreads();
    #pragma unroll
    for (int p = 0; p < 2; ++p) {
        int idx = p * 256 + tid;
        int rr = idx >> 2;
        int cc = (idx & 3) * 16;
        int r = row0 + rr;
        if (r < NN)
            *(u32x4*)&t2q[(size_t)r * 64 + cc] = *(u32x4*)&stg[rr * 64 + cc];
    }
}

// ---------------- BN stats ----------------

__global__ void bn_finalize8_kernel(const float* __restrict__ part8,
                                    const float* __restrict__ g,
                                    const float* __restrict__ be,
                                    float* __restrict__ ss) {
    int t = threadIdx.x;
    float s1 = 0.f, s2 = 0.f;
    #pragma unroll
    for (int x = 0; x < 8; ++x) {
        s1 += part8[x * 512 + t];
        s2 += part8[x * 512 + 256 + t];
    }
    float mean = s1 * (1.0f / NN);
    float var = s2 * (1.0f / NN) - mean * mean;
    float sc = g[t] * rsqrtf(var + 1e-5f);
    ss[t] = sc;
    ss[HD + t] = be[t] - mean * sc;
}

__global__ __launch_bounds__(256) void bn_part8_kernel(const unsigned* __restrict__ h,
                                                       float* __restrict__ part) {
    int tid = threadIdx.x;
    int fg = tid & 63;
    int rg = tid >> 6;
    float s1[4] = {}, s2[4] = {};
    for (int r = blockIdx.x * 4 + rg; r < NN; r += 4096) {
        unsigned u = h[(size_t)r * 64 + fg];
        f32x2 a = __builtin_amdgcn_cvt_pk_f32_fp8((int)u, false);
        f32x2 b = __builtin_amdgcn_cvt_pk_f32_fp8((int)u, true);
        float f0 = a[0], f1 = a[1], f2 = b[0], f3 = b[1];
        s1[0] += f0; s2[0] += f0 * f0;
        s1[1] += f1; s2[1] += f1 * f1;
        s1[2] += f2; s2[2] += f2 * f2;
        s1[3] += f3; s2[3] += f3 * f3;
    }
    __shared__ float sm[256][8];
    #pragma unroll
    for (int j = 0; j < 4; ++j) { sm[tid][j] = s1[j]; sm[tid][4 + j] = s2[j]; }
    __syncthreads();
    if (tid < 64) {
        float o1[4] = {}, o2[4] = {};
        #pragma unroll
        for (int r = 0; r < 4; ++r)
            #pragma unroll
            for (int j = 0; j < 4; ++j) {
                o1[j] += sm[r * 64 + tid][j];
                o2[j] += sm[r * 64 + tid][4 + j];
            }
        #pragma unroll
        for (int j = 0; j < 4; ++j) {
            part[(size_t)blockIdx.x * 512 + tid * 4 + j] = o1[j];
            part[(size_t)blockIdx.x * 512 + 256 + tid * 4 + j] = o2[j];
        }
    }
}

__global__ __launch_bounds__(256) void bn_reduce_kernel(const float* __restrict__ part,
                                                        const float* __restrict__ g,
                                                        const float* __restrict__ be,
                                                        float* __restrict__ ss) {
    int f = blockIdx.x * 32 + (threadIdx.x & 31);
    int c = threadIdx.x >> 5;
    float s1 = 0.f, s2 = 0.f;
    for (int b = c; b < 1024; b += 8) {
        s1 += part[(size_t)b * 512 + f];
        s2 += part[(size_t)b * 512 + 256 + f];
    }
    __shared__ float m1[8][32], m2[8][32];
    m1[c][threadIdx.x & 31] = s1; m2[c][threadIdx.x & 31] = s2;
    __syncthreads();
    if (threadIdx.x < 32) {
        float t1 = 0.f, t2 = 0.f;
        #pragma unroll
        for (int q = 0; q < 8; ++q) { t1 += m1[q][threadIdx.x]; t2 += m2[q][threadIdx.x]; }
        float mean = t1 * (1.0f / NN);
        float var = t2 * (1.0f / NN) - mean * mean;
        float sc = g[f] * rsqrtf(var + 1e-5f);
        ss[f] = sc;
        ss[HD + f] = be[f] - mean * sc;
    }
}

// ---------------- launch ----------------

extern "C" void kernel_launch(void* const* d_in, const int* in_sizes, int n_in,
                              void* d_out, int out_size, void* d_ws, size_t ws_size,
                              hipStream_t stream) {
    const float* x   = (const float*)d_in[0];
    const int*   ei  = (const int*)d_in[1];
    const float* W0  = (const float*)d_in[3];
    const float* g0  = (const float*)d_in[5];
    const float* be0 = (const float*)d_in[6];
    const float* W1  = (const float*)d_in[7];
    const float* g1  = (const float*)d_in[9];
    const float* be1 = (const float*)d_in[10];
    const float* W2  = (const float*)d_in[11];
    const float* b2  = (const float*)d_in[12];
    float* out = (float*)d_out;

    const int* src = ei;            // edge_index[0]
    const int* dst = ei + NE;       // edge_index[1]

    const size_t S = 51200000;                        // 100000*256*2 bytes
    char* ws = (char*)d_ws;
    unsigned*       xq  = (unsigned*)ws;
    unsigned*       t1q = (unsigned*)ws;
    unsigned char*  t2q = (unsigned char*)ws;
    _Float16*       a0  = (_Float16*)(ws + 25600000); // [NN][128] fp16 (25.6MB)
    _Float16*       S2  = (_Float16*)(ws + S);        // h0 (fp16) / h1q (fp8) slot
    unsigned*       h1q = (unsigned*)(ws + S);
    char* base2 = ws + 2 * S;
    int*   csr  = (int*)  (base2);                    // 12.8MB
    int*   offs = (int*)  (base2 + 12800000);
    float* dinv = (float*)(base2 + 13200064);
    float* ssb  = (float*)(base2 + 13602112);
    int*   btot = (int*)  (base2 + 13604160);
    int*   bbase= (int*)  (base2 + 13605184);
    _Float16* wt0 = (_Float16*)(base2 + 13608320);    // [256][128]
    _Float16* wt1 = (_Float16*)(base2 + 13673856);    // [256][256]
    _Float16* wt2 = (_Float16*)(base2 + 13804928);    // [64][256]
    int*   hist = (int*)  (base2 + 13837696);         // NBKT*G ints
    int*   epk  = (int*)  (base2 + 14640576);         // NE ints = 12.8MB
    float* part = (float*)(base2 + 27440576);         // 1024*512 floats = 2MB
    float* part8= (float*)(base2 + 29537728);         // 8*512 floats = 16KB

    // CSR build: bucketed counting sort
    hist_kernel<<<G, 256, 0, stream>>>(dst, hist);
    rowscan_kernel<<<NBKT, 256, 0, stream>>>(hist, btot);
    totscan_kernel<<<1, 256, 0, stream>>>(btot, bbase);
    scatter_kernel<<<G, 256, 0, stream>>>(src, dst, hist, bbase, epk);
    bucket_fill_kernel<<<NBKT, 256, 0, stream>>>(bbase, epk, csr, offs, dinv);

    // weights -> fp16 transposed (one launch)
    wtrans_all_kernel<<<448, 256, 0, stream>>>(W0, W1, W2, wt0, wt1, wt2);

    const int MB = (NN + 127) / 128;   // 782

    // Layer 0: a0 = D^-1/2 (A+I) D^-1/2 x (fp8 gather); h0 = a0 @ W0 (+fused BN stats)
    hipMemsetAsync(part8, 0, 8 * 512 * sizeof(float), stream);
    conv_x_kernel<<<(NN * FIN / 4 + 255) / 256, 256, 0, stream>>>(x, dinv, xq);
    agg128_kernel<<<NN / 4, 256, 0, stream>>>(xq, offs, csr, dinv, a0);
    mfma_gemm_big<FIN, false, false, false, true><<<MB * 2, 256, 0, stream>>>(
        a0, FIN, wt0, nullptr, dinv, S2, HD, part8);            // h0 -> S2 (fp16)
    bn_finalize8_kernel<<<1, HD, 0, stream>>>(part8, g0, be0, ssb);

    // Layer 1: t1 = dinv * (relu(bn(h0)) @ W1) -> fp8; h1 = dinv*(A+I)t1 -> fp8
    mfma_gemm_big<HD, true, true, true, false><<<MB * 2, 256, 0, stream>>>(
        S2, HD, wt1, ssb, dinv, t1q, HD, nullptr);              // t1q -> slot A
    agg256_kernel<<<NN / 4, 256, 0, stream>>>(t1q, offs, csr, dinv, h1q);  // h1q -> S2

    bn_part8_kernel<<<1024, 256, 0, stream>>>(h1q, part);
    bn_reduce_kernel<<<8, 256, 0, stream>>>(part, g1, be1, ssb);

    // Layer 2: t2 = dinv * (relu(bn(h1)) @ W2) -> fp8 64B rows; agg + log_softmax
    mfma_gemm2_kernel<<<MB, 256, 0, stream>>>(h1q, wt2, ssb, dinv, t2q);
    agg47_lsm_kernel<<<NN / 4, 256, 0, stream>>>((const unsigned*)t2q, offs, csr, dinv, b2, out);
}